// Round 7
// baseline (395.071 us; speedup 1.0000x reference)
//
#include <hip/hip_runtime.h>

constexpr int BB = 8;
constexpr int HH = 1024;
constexpr int WW = 1024;
constexpr int HW = HH * WW;
constexpr int TOTAL = BB * HW;

constexpr float RADIUS = 15.0f;
constexpr float THR_VOTES = 0.01f;
constexpr float THR_PEAKS = 0.2f;
// pi * 15^2 in double, rounded to f32 (matches jnp: votes / (np.pi*R*R))
constexpr float DIVISOR = 706.8583470577035f;

constexpr int TS = 64;          // gather output tile (16 KB LDS -> 8 blocks/CU)
constexpr int AP = 48;          // apron: votes with |delta|<=48 are "near"
constexpr int RG = TS + 2 * AP; // 160 input region per tile
constexpr int RGF = RG / 4;     // 40 float4 units per region row
constexpr int NF4 = RG * RGF;   // 6400 float4 units per region
constexpr int TPB = 256;
constexpr int FAR_CAP = (TOTAL - 16) / 2;

// ---------------------------------------------------------------------------
// Pass 1: gather votes, float4-wide, XCD-affine. Block -> (b = blk&7,
// t = blk>>3): XCD x owns batch image x (dispatch round-robins blk%8), tiles
// swept row-major so apron re-reads stay in the XCD's private L2 (~1.9 MB
// working set vs 4 MB). 8 blocks/CU (16 KB LDS, 256 thr) = 32 waves/CU.
// Near votes (|delta|<=48) accumulate in the target tile's LDS; far votes
// are appended to a compact list by the SOURCE pixel's tile (exactly-once).
// ---------------------------------------------------------------------------
__device__ __forceinline__ void process4(int px0, int py, float4 kw, float4 fox,
                                         float4 foy, int tx0, int ty0, int b,
                                         float* tile, float* farbuf) {
    const float w[4]  = {kw.x, kw.y, kw.z, kw.w};
    const float ox[4] = {fox.x, fox.y, fox.z, fox.w};
    const float oy[4] = {foy.x, foy.y, foy.z, foy.w};
#pragma unroll
    for (int j = 0; j < 4; ++j) {
        const int px = px0 + j;
        // forbid FMA contraction: must match numpy's mul-then-add rounding,
        // else a .5-boundary vote lands in the adjacent cell.
        const float fx = __fadd_rn((float)px, __fmul_rn(RADIUS, ox[j]));
        const float fy = __fadd_rn((float)py, __fmul_rn(RADIUS, oy[j]));
        const int vx = (int)rintf(fx);   // round-half-even == np.round
        const int vy = (int)rintf(fy);
        if (vx < 0 || vx >= WW || vy < 0 || vy >= HH || w[j] < THR_VOTES) continue;
        const int dx = vx - px, dy = vy - py;
        if (dx >= -AP && dx <= AP && dy >= -AP && dy <= AP) {
            const int lx = vx - tx0, ly = vy - ty0;
            if (lx >= 0 && lx < TS && ly >= 0 && ly < TS)
                atomicAdd(&tile[ly * TS + lx], w[j]);
        } else if (px >= tx0 && px < tx0 + TS && py >= ty0 && py < ty0 + TS) {
            const int slot = atomicAdd((int*)farbuf, 1);
            if (slot < FAR_CAP) {
                ((int*)farbuf)[16 + 2 * slot] = b * HW + vy * WW + vx;
                farbuf[17 + 2 * slot] = w[j];
            }
        }
    }
}

__global__ __launch_bounds__(TPB, 8)
void gather_votes(const float* __restrict__ kp, const float* __restrict__ off,
                  float* __restrict__ vraw, float* __restrict__ farbuf) {
    __shared__ float tile[TS * TS];   // 16 KB
    const int blk = blockIdx.x;       // 2048 blocks
    const int b   = blk & 7;          // batch == XCD (blk%8 round-robin)
    const int t   = blk >> 3;         // 256 tiles, row-major sweep per XCD
    const int ty0 = (t >> 4) * TS;
    const int tx0 = (t & 15) * TS;

    float4* tf4 = (float4*)tile;
    for (int j = threadIdx.x; j < TS * TS / 4; j += TPB)
        tf4[j] = make_float4(0.f, 0.f, 0.f, 0.f);
    __syncthreads();

    const float* kpb  = kp  + (long)b * HW;
    const float* offx = off + (long)b * 2 * HW;
    const float* offy = offx + HW;

    for (int u = threadIdx.x; u < NF4; u += 2 * TPB) {
        const int uB = u + TPB;
        // decode unit A
        const int rA  = u / RGF;
        const int cA  = u - rA * RGF;
        const int pyA = ty0 - AP + rA;
        const int pxA = tx0 - AP + 4 * cA;   // multiple of 4: f4 never straddles edge
        const bool okA = (pyA >= 0 && pyA < HH && pxA >= 0 && pxA <= WW - 4);
        // decode unit B
        const int rB  = uB / RGF;
        const int cB  = uB - rB * RGF;
        const int pyB = ty0 - AP + rB;
        const int pxB = tx0 - AP + 4 * cB;
        const bool okB = (uB < NF4 && pyB >= 0 && pyB < HH && pxB >= 0 && pxB <= WW - 4);

        float4 kA, xA, yA, kB, xB, yB;
        if (okA) {
            const long p = (long)pyA * WW + pxA;
            kA = *(const float4*)(kpb + p);
            xA = *(const float4*)(offx + p);
            yA = *(const float4*)(offy + p);
        }
        if (okB) {
            const long p = (long)pyB * WW + pxB;
            kB = *(const float4*)(kpb + p);
            xB = *(const float4*)(offx + p);
            yB = *(const float4*)(offy + p);
        }
        if (okA) process4(pxA, pyA, kA, xA, yA, tx0, ty0, b, tile, farbuf);
        if (okB) process4(pxB, pyB, kB, xB, yB, tx0, ty0, b, tile, farbuf);
    }
    __syncthreads();

    float* vb = vraw + (long)b * HW;
    for (int j = threadIdx.x; j < TS * TS / 4; j += TPB) {
        const int r  = j / (TS / 4);
        const int c4 = j % (TS / 4);
        *(float4*)&vb[(ty0 + r) * WW + tx0 + c4 * 4] = tf4[j];
    }
}

// Pass 1b: flush the (tiny) far-vote list with global atomics.
__global__ void far_scatter(const float* __restrict__ farbuf,
                            float* __restrict__ vraw) {
    const int n = min(((const int*)farbuf)[0], FAR_CAP);
    const int stride = gridDim.x * blockDim.x;
    for (int i = blockIdx.x * blockDim.x + threadIdx.x; i < n; i += stride) {
        const int tg = ((const int*)farbuf)[16 + 2 * i];
        atomicAdd(&vraw[tg], farbuf[17 + 2 * i]);
    }
}

// ---------------------------------------------------------------------------
// Pass 2: 15x15 box-sum, separable, /DIVISOR folded into row pass.
// ---------------------------------------------------------------------------
__global__ __launch_bounds__(256)
void box_row(const float* __restrict__ in, float* __restrict__ out) {
    const long base = (long)blockIdx.x * WW;   // one image row per block
    const int c0 = threadIdx.x * 4;
    float v[20];
#pragma unroll
    for (int k = 0; k < 5; ++k) {
        const int c = c0 - 8 + 4 * k;
        float4 f = (c >= 0 && c <= WW - 4) ? *(const float4*)&in[base + c]
                                           : make_float4(0.f, 0.f, 0.f, 0.f);
        v[4 * k + 0] = f.x; v[4 * k + 1] = f.y;
        v[4 * k + 2] = f.z; v[4 * k + 3] = f.w;
    }
    float s = 0.f;
#pragma unroll
    for (int k = 1; k <= 15; ++k) s += v[k];
    float4 o;
    o.x = s / DIVISOR;
    s += v[16] - v[1];  o.y = s / DIVISOR;
    s += v[17] - v[2];  o.z = s / DIVISOR;
    s += v[18] - v[3];  o.w = s / DIVISOR;
    *(float4*)&out[base + c0] = o;
}

// 8 vertical outputs per thread (rows r0..r0+7) from 22 coalesced reads.
__global__ __launch_bounds__(256)
void box_col(const float* __restrict__ in, float* __restrict__ out) {
    const int bi = blockIdx.x;               // 4096 = 8b * 128rg * 4xg
    const int xg = bi & 3;
    const int rg = (bi >> 2) & 127;
    const int b  = bi >> 9;
    const int x  = xg * 256 + threadIdx.x;
    const int r0 = rg * 8;
    const float* p = in + (long)b * HW + x;
    float v[22];
#pragma unroll
    for (int k = 0; k < 22; ++k) {
        const int r = r0 - 7 + k;
        v[k] = (r >= 0 && r < HH) ? p[(long)r * WW] : 0.f;
    }
    float s = 0.f;
#pragma unroll
    for (int k = 0; k < 15; ++k) s += v[k];
    float* q = out + (long)b * HW + x;
    q[(long)r0 * WW] = s;
#pragma unroll
    for (int j = 1; j < 8; ++j) {
        s += v[14 + j] - v[j - 1];
        q[(long)(r0 + j) * WW] = s;
    }
}

// ---------------------------------------------------------------------------
// Pass 3: 17x17 max-pool, separable; col pass fused with the peak decision.
// ---------------------------------------------------------------------------
__global__ __launch_bounds__(256)
void max_row(const float* __restrict__ in, float* __restrict__ out) {
    const long base = (long)blockIdx.x * WW;
    const int c0 = threadIdx.x * 4;
    float v[20];
#pragma unroll
    for (int k = 0; k < 5; ++k) {
        const int c = c0 - 8 + 4 * k;
        float4 f = (c >= 0 && c <= WW - 4)
                       ? *(const float4*)&in[base + c]
                       : make_float4(-INFINITY, -INFINITY, -INFINITY, -INFINITY);
        v[4 * k + 0] = f.x; v[4 * k + 1] = f.y;
        v[4 * k + 2] = f.z; v[4 * k + 3] = f.w;
    }
    float m = v[3];
#pragma unroll
    for (int k = 4; k <= 16; ++k) m = fmaxf(m, v[k]);   // common v[3..16]
    float4 o;
    o.x = fmaxf(fmaxf(m, v[0]),  fmaxf(v[1],  v[2]));
    o.y = fmaxf(fmaxf(m, v[1]),  fmaxf(v[2],  v[17]));
    o.z = fmaxf(fmaxf(m, v[2]),  fmaxf(v[17], v[18]));
    o.w = fmaxf(fmaxf(m, v[17]), fmaxf(v[18], v[19]));
    *(float4*)&out[base + c0] = o;
}

// 8 vertical outputs per thread via suffix/prefix max over 24 rows; fused peaks.
__global__ __launch_bounds__(256)
void max_col_peaks(const float* __restrict__ rowmaxed,
                   const float* __restrict__ votes,
                   float* __restrict__ peaks) {
    const int bi = blockIdx.x;               // 4096 = 8b * 128rg * 4xg
    const int xg = bi & 3;
    const int rg = (bi >> 2) & 127;
    const int b  = bi >> 9;
    const int x  = xg * 256 + threadIdx.x;
    const int r0 = rg * 8;
    const float* p = rowmaxed + (long)b * HW + x;
    float v[24];
#pragma unroll
    for (int k = 0; k < 24; ++k) {
        const int r = r0 - 8 + k;
        v[k] = (r >= 0 && r < HH) ? p[(long)r * WW] : -INFINITY;
    }
    // output j (0..7) needs max(v[j .. j+16]). suf[j]=max(v[j..16]);
    // pre accumulates v[17..16+j].
    float suf[17];
    suf[16] = v[16];
#pragma unroll
    for (int k = 15; k >= 0; --k) suf[k] = fmaxf(v[k], suf[k + 1]);

    const float* vp = votes + (long)b * HW + x;
    float* q = peaks + (long)b * HW + x;
    float pre = -INFINITY;
#pragma unroll
    for (int j = 0; j < 8; ++j) {
        if (j > 0) pre = fmaxf(pre, v[16 + j]);
        const float d = fmaxf(suf[j], pre);
        const float vv = vp[(long)(r0 + j) * WW];
        // np.isclose(votes, dilated): |a-b| <= atol + rtol*|b|, b = dilated
        const bool close = fabsf(vv - d) <= (1e-8f + 1e-5f * fabsf(d));
        q[(long)(r0 + j) * WW] = (close && vv > THR_PEAKS) ? 1.0f : 0.0f;
    }
}

extern "C" void kernel_launch(void* const* d_in, const int* in_sizes, int n_in,
                              void* d_out, int out_size, void* d_ws, size_t ws_size,
                              hipStream_t stream) {
    const float* kp  = (const float*)d_in[0];
    const float* off = (const float*)d_in[1];
    float* V = (float*)d_out;            // smoothed votes -> output 0
    float* P = (float*)d_out + TOTAL;    // peaks -> output 1 (scratch earlier)
    float* W = (float*)d_ws;             // 32 MB scratch: raw votes, then rowmax

    // P region lifecycle: far-list -> row-boxsum temp -> final peaks.
    // W region lifecycle: raw votes -> row-max temp.
    hipMemsetAsync(P, 0, sizeof(int), stream);                 // far counter
    gather_votes <<<2048, TPB, 0, stream>>>(kp, off, W, P);    // W = raw votes
    far_scatter  <<<256,  256, 0, stream>>>(P, W);             // + far votes
    box_row      <<<8192, 256, 0, stream>>>(W, P);             // P = rowsum/D
    box_col      <<<4096, 256, 0, stream>>>(P, V);             // V = smoothed
    max_row      <<<8192, 256, 0, stream>>>(V, W);             // W = rowmax
    max_col_peaks<<<4096, 256, 0, stream>>>(W, V, P);          // P = peaks
}

// Round 8
// 233.042 us; speedup vs baseline: 1.6953x; 1.6953x over previous
//
#include <hip/hip_runtime.h>

constexpr int BB = 8;
constexpr int HH = 1024;
constexpr int WW = 1024;
constexpr int HW = HH * WW;
constexpr int TOTAL = BB * HW;

constexpr float RADIUS = 15.0f;
constexpr float THR_VOTES = 0.01f;
constexpr float THR_PEAKS = 0.2f;
// pi * 15^2 in double, rounded to f32 (matches jnp: votes / (np.pi*R*R))
constexpr float DIVISOR = 706.8583470577035f;

constexpr int TS = 64;          // gather output tile (16 KB LDS -> 8 blocks/CU)
constexpr int AP = 48;          // apron: votes with |delta|<=48 are "near"
constexpr int RG = TS + 2 * AP; // 160 input region per tile
constexpr int RGF = RG / 4;     // 40 float4 units per region row
constexpr int NF4 = RG * RGF;   // 6400 float4 units per region
constexpr int TPB = 256;
constexpr int NBLK = 2048;      // gather blocks
constexpr int FCAP = 128;       // far-vote capacity per block (expect ~11)

// far-list layout in the P region (ints): counts[NBLK], idx[NBLK*FCAP],
// then weights (floats) at wbase.
constexpr int FIDX0 = NBLK;
constexpr int FW0   = NBLK + NBLK * FCAP;

// ---------------------------------------------------------------------------
// Pass 1: gather votes, float4-wide, XCD-affine (b = blk&7 -> XCD owns one
// batch image; tiles swept row-major keep apron re-reads in the XCD L2).
// Near votes (|delta|<=48) accumulate in the target tile's LDS. Far votes
// (~11 per block) stage in an LDS list counted by an LDS atomic -- NO global
// counter (round-7 lesson: ~20K wave-aggregated RMWs on ONE cache line
// serialized at its home L2 and pinned the kernel at ~237 us regardless of
// occupancy). Each block flushes its list to a private global segment.
// ---------------------------------------------------------------------------
__device__ __forceinline__ void process4(int px0, int py, float4 kw, float4 fox,
                                         float4 foy, int tx0, int ty0, int b,
                                         float* tile, int* lcnt,
                                         int* lidx, float* lw) {
    const float w[4]  = {kw.x, kw.y, kw.z, kw.w};
    const float ox[4] = {fox.x, fox.y, fox.z, fox.w};
    const float oy[4] = {foy.x, foy.y, foy.z, foy.w};
#pragma unroll
    for (int j = 0; j < 4; ++j) {
        const int px = px0 + j;
        // forbid FMA contraction: must match numpy's mul-then-add rounding,
        // else a .5-boundary vote lands in the adjacent cell.
        const float fx = __fadd_rn((float)px, __fmul_rn(RADIUS, ox[j]));
        const float fy = __fadd_rn((float)py, __fmul_rn(RADIUS, oy[j]));
        const int vx = (int)rintf(fx);   // round-half-even == np.round
        const int vy = (int)rintf(fy);
        if (vx < 0 || vx >= WW || vy < 0 || vy >= HH || w[j] < THR_VOTES) continue;
        const int dx = vx - px, dy = vy - py;
        if (dx >= -AP && dx <= AP && dy >= -AP && dy <= AP) {
            const int lx = vx - tx0, ly = vy - ty0;
            if (lx >= 0 && lx < TS && ly >= 0 && ly < TS)
                atomicAdd(&tile[ly * TS + lx], w[j]);
        } else if (px >= tx0 && px < tx0 + TS && py >= ty0 && py < ty0 + TS) {
            // far vote, owned by the SOURCE pixel's tile (exactly-once).
            const int slot = atomicAdd(lcnt, 1);   // LDS atomic: no global line
            if (slot < FCAP) {
                lidx[slot] = b * HW + vy * WW + vx;
                lw[slot]   = w[j];
            }
        }
    }
}

__global__ __launch_bounds__(TPB, 8)
void gather_votes(const float* __restrict__ kp, const float* __restrict__ off,
                  float* __restrict__ vraw, float* __restrict__ farbuf) {
    __shared__ float tile[TS * TS];   // 16 KB
    __shared__ int   lidx[FCAP];
    __shared__ float lw[FCAP];
    __shared__ int   lcnt;
    const int blk = blockIdx.x;       // 2048 blocks
    const int b   = blk & 7;          // batch == XCD (blk%8 round-robin)
    const int t   = blk >> 3;         // 256 tiles, row-major sweep per XCD
    const int ty0 = (t >> 4) * TS;
    const int tx0 = (t & 15) * TS;

    if (threadIdx.x == 0) lcnt = 0;
    float4* tf4 = (float4*)tile;
    for (int j = threadIdx.x; j < TS * TS / 4; j += TPB)
        tf4[j] = make_float4(0.f, 0.f, 0.f, 0.f);
    __syncthreads();

    const float* kpb  = kp  + (long)b * HW;
    const float* offx = off + (long)b * 2 * HW;
    const float* offy = offx + HW;

    for (int u = threadIdx.x; u < NF4; u += 2 * TPB) {
        const int uB = u + TPB;
        // decode unit A
        const int rA  = u / RGF;
        const int cA  = u - rA * RGF;
        const int pyA = ty0 - AP + rA;
        const int pxA = tx0 - AP + 4 * cA;   // multiple of 4: f4 never straddles edge
        const bool okA = (pyA >= 0 && pyA < HH && pxA >= 0 && pxA <= WW - 4);
        // decode unit B
        const int rB  = uB / RGF;
        const int cB  = uB - rB * RGF;
        const int pyB = ty0 - AP + rB;
        const int pxB = tx0 - AP + 4 * cB;
        const bool okB = (uB < NF4 && pyB >= 0 && pyB < HH && pxB >= 0 && pxB <= WW - 4);

        float4 kA, xA, yA, kB, xB, yB;
        if (okA) {
            const long p = (long)pyA * WW + pxA;
            kA = *(const float4*)(kpb + p);
            xA = *(const float4*)(offx + p);
            yA = *(const float4*)(offy + p);
        }
        if (okB) {
            const long p = (long)pyB * WW + pxB;
            kB = *(const float4*)(kpb + p);
            xB = *(const float4*)(offx + p);
            yB = *(const float4*)(offy + p);
        }
        if (okA) process4(pxA, pyA, kA, xA, yA, tx0, ty0, b, tile, &lcnt, lidx, lw);
        if (okB) process4(pxB, pyB, kB, xB, yB, tx0, ty0, b, tile, &lcnt, lidx, lw);
    }
    __syncthreads();

    // flush tile (plain coalesced stores; tiles partition the image)
    float* vb = vraw + (long)b * HW;
    for (int j = threadIdx.x; j < TS * TS / 4; j += TPB) {
        const int r  = j / (TS / 4);
        const int c4 = j % (TS / 4);
        *(float4*)&vb[(ty0 + r) * WW + tx0 + c4 * 4] = tf4[j];
    }
    // flush far list to this block's private segment (no contention)
    const int n = min(lcnt, FCAP);
    int* fi = (int*)farbuf;
    if (threadIdx.x == 0) fi[blk] = n;
    for (int j = threadIdx.x; j < n; j += TPB) {
        fi[FIDX0 + blk * FCAP + j] = lidx[j];
        farbuf[FW0 + blk * FCAP + j] = lw[j];
    }
}

// Pass 1b: flush the (tiny) per-block far-vote segments with global atomics.
__global__ void far_scatter(const float* __restrict__ farbuf,
                            float* __restrict__ vraw) {
    const int s = blockIdx.x * blockDim.x + threadIdx.x;
    if (s >= NBLK * FCAP) return;
    const int blk = s / FCAP;
    const int j   = s % FCAP;
    const int* fi = (const int*)farbuf;
    if (j < min(fi[blk], FCAP))
        atomicAdd(&vraw[fi[FIDX0 + blk * FCAP + j]], farbuf[FW0 + blk * FCAP + j]);
}

// ---------------------------------------------------------------------------
// Pass 2: 15x15 box-sum, separable, /DIVISOR folded into row pass.
// ---------------------------------------------------------------------------
__global__ __launch_bounds__(256)
void box_row(const float* __restrict__ in, float* __restrict__ out) {
    const long base = (long)blockIdx.x * WW;   // one image row per block
    const int c0 = threadIdx.x * 4;
    float v[20];
#pragma unroll
    for (int k = 0; k < 5; ++k) {
        const int c = c0 - 8 + 4 * k;
        float4 f = (c >= 0 && c <= WW - 4) ? *(const float4*)&in[base + c]
                                           : make_float4(0.f, 0.f, 0.f, 0.f);
        v[4 * k + 0] = f.x; v[4 * k + 1] = f.y;
        v[4 * k + 2] = f.z; v[4 * k + 3] = f.w;
    }
    float s = 0.f;
#pragma unroll
    for (int k = 1; k <= 15; ++k) s += v[k];
    float4 o;
    o.x = s / DIVISOR;
    s += v[16] - v[1];  o.y = s / DIVISOR;
    s += v[17] - v[2];  o.z = s / DIVISOR;
    s += v[18] - v[3];  o.w = s / DIVISOR;
    *(float4*)&out[base + c0] = o;
}

// 8 vertical outputs per thread (rows r0..r0+7) from 22 coalesced reads.
__global__ __launch_bounds__(256)
void box_col(const float* __restrict__ in, float* __restrict__ out) {
    const int bi = blockIdx.x;               // 4096 = 8b * 128rg * 4xg
    const int xg = bi & 3;
    const int rg = (bi >> 2) & 127;
    const int b  = bi >> 9;
    const int x  = xg * 256 + threadIdx.x;
    const int r0 = rg * 8;
    const float* p = in + (long)b * HW + x;
    float v[22];
#pragma unroll
    for (int k = 0; k < 22; ++k) {
        const int r = r0 - 7 + k;
        v[k] = (r >= 0 && r < HH) ? p[(long)r * WW] : 0.f;
    }
    float s = 0.f;
#pragma unroll
    for (int k = 0; k < 15; ++k) s += v[k];
    float* q = out + (long)b * HW + x;
    q[(long)r0 * WW] = s;
#pragma unroll
    for (int j = 1; j < 8; ++j) {
        s += v[14 + j] - v[j - 1];
        q[(long)(r0 + j) * WW] = s;
    }
}

// ---------------------------------------------------------------------------
// Pass 3: 17x17 max-pool, separable; col pass fused with the peak decision.
// ---------------------------------------------------------------------------
__global__ __launch_bounds__(256)
void max_row(const float* __restrict__ in, float* __restrict__ out) {
    const long base = (long)blockIdx.x * WW;
    const int c0 = threadIdx.x * 4;
    float v[20];
#pragma unroll
    for (int k = 0; k < 5; ++k) {
        const int c = c0 - 8 + 4 * k;
        float4 f = (c >= 0 && c <= WW - 4)
                       ? *(const float4*)&in[base + c]
                       : make_float4(-INFINITY, -INFINITY, -INFINITY, -INFINITY);
        v[4 * k + 0] = f.x; v[4 * k + 1] = f.y;
        v[4 * k + 2] = f.z; v[4 * k + 3] = f.w;
    }
    float m = v[3];
#pragma unroll
    for (int k = 4; k <= 16; ++k) m = fmaxf(m, v[k]);   // common v[3..16]
    float4 o;
    o.x = fmaxf(fmaxf(m, v[0]),  fmaxf(v[1],  v[2]));
    o.y = fmaxf(fmaxf(m, v[1]),  fmaxf(v[2],  v[17]));
    o.z = fmaxf(fmaxf(m, v[2]),  fmaxf(v[17], v[18]));
    o.w = fmaxf(fmaxf(m, v[17]), fmaxf(v[18], v[19]));
    *(float4*)&out[base + c0] = o;
}

// 8 vertical outputs per thread via suffix/prefix max over 24 rows; fused peaks.
__global__ __launch_bounds__(256)
void max_col_peaks(const float* __restrict__ rowmaxed,
                   const float* __restrict__ votes,
                   float* __restrict__ peaks) {
    const int bi = blockIdx.x;               // 4096 = 8b * 128rg * 4xg
    const int xg = bi & 3;
    const int rg = (bi >> 2) & 127;
    const int b  = bi >> 9;
    const int x  = xg * 256 + threadIdx.x;
    const int r0 = rg * 8;
    const float* p = rowmaxed + (long)b * HW + x;
    float v[24];
#pragma unroll
    for (int k = 0; k < 24; ++k) {
        const int r = r0 - 8 + k;
        v[k] = (r >= 0 && r < HH) ? p[(long)r * WW] : -INFINITY;
    }
    // output j (0..7) needs max(v[j .. j+16]). suf[j]=max(v[j..16]);
    // pre accumulates v[17..16+j].
    float suf[17];
    suf[16] = v[16];
#pragma unroll
    for (int k = 15; k >= 0; --k) suf[k] = fmaxf(v[k], suf[k + 1]);

    const float* vp = votes + (long)b * HW + x;
    float* q = peaks + (long)b * HW + x;
    float pre = -INFINITY;
#pragma unroll
    for (int j = 0; j < 8; ++j) {
        if (j > 0) pre = fmaxf(pre, v[16 + j]);
        const float d = fmaxf(suf[j], pre);
        const float vv = vp[(long)(r0 + j) * WW];
        // np.isclose(votes, dilated): |a-b| <= atol + rtol*|b|, b = dilated
        const bool close = fabsf(vv - d) <= (1e-8f + 1e-5f * fabsf(d));
        q[(long)(r0 + j) * WW] = (close && vv > THR_PEAKS) ? 1.0f : 0.0f;
    }
}

extern "C" void kernel_launch(void* const* d_in, const int* in_sizes, int n_in,
                              void* d_out, int out_size, void* d_ws, size_t ws_size,
                              hipStream_t stream) {
    const float* kp  = (const float*)d_in[0];
    const float* off = (const float*)d_in[1];
    float* V = (float*)d_out;            // smoothed votes -> output 0
    float* P = (float*)d_out + TOTAL;    // peaks -> output 1 (scratch earlier)
    float* W = (float*)d_ws;             // 32 MB scratch: raw votes, then rowmax

    // P region lifecycle: far-vote segments -> row-boxsum temp -> final peaks.
    // W region lifecycle: raw votes -> row-max temp.
    gather_votes <<<NBLK, TPB, 0, stream>>>(kp, off, W, P);    // W = raw votes
    far_scatter  <<<NBLK * FCAP / 256, 256, 0, stream>>>(P, W);
    box_row      <<<8192, 256, 0, stream>>>(W, P);             // P = rowsum/D
    box_col      <<<4096, 256, 0, stream>>>(P, V);             // V = smoothed
    max_row      <<<8192, 256, 0, stream>>>(V, W);             // W = rowmax
    max_col_peaks<<<4096, 256, 0, stream>>>(W, V, P);          // P = peaks
}

// Round 10
// 222.167 us; speedup vs baseline: 1.7783x; 1.0489x over previous
//
#include <hip/hip_runtime.h>

constexpr int BB = 8;
constexpr int HH = 1024;
constexpr int WW = 1024;
constexpr int HW = HH * WW;
constexpr int TOTAL = BB * HW;

constexpr float RADIUS = 15.0f;
constexpr float THR_VOTES = 0.01f;
constexpr float THR_PEAKS = 0.2f;
// pi * 15^2 in double, rounded to f32 (matches jnp: votes / (np.pi*R*R))
constexpr float DIVISOR = 706.8583470577035f;

constexpr int TS = 64;          // gather output tile (16 KB LDS -> 8 blocks/CU)
constexpr int AP = 48;          // apron: votes with |delta|<=48 are "near"
constexpr int RG = TS + 2 * AP; // 160 input region per tile
constexpr int RGF = RG / 4;     // 40 float4 units per region row
constexpr int NF4 = RG * RGF;   // 6400 float4 units per region
constexpr int TPB = 256;
constexpr int NBLK = 2048;      // gather blocks
constexpr int FCAP = 128;       // far-vote capacity per block (expect ~11)

// far-list layout in the P region (ints): counts[NBLK], idx[NBLK*FCAP],
// then weights (floats) at FW0.
constexpr int FIDX0 = NBLK;
constexpr int FW0   = NBLK + NBLK * FCAP;

// 2D-fused smoothing/max tiles
constexpr int BT = 64;          // output tile
constexpr int BH = 8;           // halo (box needs 7, max needs 8; use 8)
constexpr int BR = BT + 2 * BH; // 80 staged region

// ---------------------------------------------------------------------------
// Pass 1: gather votes, float4-wide, XCD-affine (b = blk&7 -> XCD owns one
// batch image; tiles swept row-major keep apron re-reads in the XCD L2).
// Near votes (|delta|<=48) accumulate in the target tile's LDS. Far votes
// (~11 per block) stage in an LDS list counted by an LDS atomic -- NO global
// counter (round-7 lesson: ~20K wave-aggregated RMWs on ONE cache line
// serialize at its home L2 and pinned the kernel at ~237 us regardless of
// occupancy). Each block flushes its list to a private global segment.
// ---------------------------------------------------------------------------
__device__ __forceinline__ void process4(int px0, int py, float4 kw, float4 fox,
                                         float4 foy, int tx0, int ty0, int b,
                                         float* tile, int* lcnt,
                                         int* lidx, float* lw) {
    const float w[4]  = {kw.x, kw.y, kw.z, kw.w};
    const float ox[4] = {fox.x, fox.y, fox.z, fox.w};
    const float oy[4] = {foy.x, foy.y, foy.z, foy.w};
#pragma unroll
    for (int j = 0; j < 4; ++j) {
        const int px = px0 + j;
        // forbid FMA contraction: must match numpy's mul-then-add rounding,
        // else a .5-boundary vote lands in the adjacent cell.
        const float fx = __fadd_rn((float)px, __fmul_rn(RADIUS, ox[j]));
        const float fy = __fadd_rn((float)py, __fmul_rn(RADIUS, oy[j]));
        const int vx = (int)rintf(fx);   // round-half-even == np.round
        const int vy = (int)rintf(fy);
        if (vx < 0 || vx >= WW || vy < 0 || vy >= HH || w[j] < THR_VOTES) continue;
        const int dx = vx - px, dy = vy - py;
        if (dx >= -AP && dx <= AP && dy >= -AP && dy <= AP) {
            const int lx = vx - tx0, ly = vy - ty0;
            if (lx >= 0 && lx < TS && ly >= 0 && ly < TS)
                atomicAdd(&tile[ly * TS + lx], w[j]);
        } else if (px >= tx0 && px < tx0 + TS && py >= ty0 && py < ty0 + TS) {
            // far vote, owned by the SOURCE pixel's tile (exactly-once).
            const int slot = atomicAdd(lcnt, 1);   // LDS atomic: no global line
            if (slot < FCAP) {
                lidx[slot] = b * HW + vy * WW + vx;
                lw[slot]   = w[j];
            }
        }
    }
}

__global__ __launch_bounds__(TPB, 8)
void gather_votes(const float* __restrict__ kp, const float* __restrict__ off,
                  float* __restrict__ vraw, float* __restrict__ farbuf) {
    __shared__ float tile[TS * TS];   // 16 KB
    __shared__ int   lidx[FCAP];
    __shared__ float lw[FCAP];
    __shared__ int   lcnt;
    const int blk = blockIdx.x;       // 2048 blocks
    const int b   = blk & 7;          // batch == XCD (blk%8 round-robin)
    const int t   = blk >> 3;         // 256 tiles, row-major sweep per XCD
    const int ty0 = (t >> 4) * TS;
    const int tx0 = (t & 15) * TS;

    if (threadIdx.x == 0) lcnt = 0;
    float4* tf4 = (float4*)tile;
    for (int j = threadIdx.x; j < TS * TS / 4; j += TPB)
        tf4[j] = make_float4(0.f, 0.f, 0.f, 0.f);
    __syncthreads();

    const float* kpb  = kp  + (long)b * HW;
    const float* offx = off + (long)b * 2 * HW;
    const float* offy = offx + HW;

    for (int u = threadIdx.x; u < NF4; u += 2 * TPB) {
        const int uB = u + TPB;
        // decode unit A
        const int rA  = u / RGF;
        const int cA  = u - rA * RGF;
        const int pyA = ty0 - AP + rA;
        const int pxA = tx0 - AP + 4 * cA;   // multiple of 4: f4 never straddles edge
        const bool okA = (pyA >= 0 && pyA < HH && pxA >= 0 && pxA <= WW - 4);
        // decode unit B
        const int rB  = uB / RGF;
        const int cB  = uB - rB * RGF;
        const int pyB = ty0 - AP + rB;
        const int pxB = tx0 - AP + 4 * cB;
        const bool okB = (uB < NF4 && pyB >= 0 && pyB < HH && pxB >= 0 && pxB <= WW - 4);

        float4 kA, xA, yA, kB, xB, yB;
        if (okA) {
            const long p = (long)pyA * WW + pxA;
            kA = *(const float4*)(kpb + p);
            xA = *(const float4*)(offx + p);
            yA = *(const float4*)(offy + p);
        }
        if (okB) {
            const long p = (long)pyB * WW + pxB;
            kB = *(const float4*)(kpb + p);
            xB = *(const float4*)(offx + p);
            yB = *(const float4*)(offy + p);
        }
        if (okA) process4(pxA, pyA, kA, xA, yA, tx0, ty0, b, tile, &lcnt, lidx, lw);
        if (okB) process4(pxB, pyB, kB, xB, yB, tx0, ty0, b, tile, &lcnt, lidx, lw);
    }
    __syncthreads();

    // flush tile (plain coalesced stores; tiles partition the image)
    float* vb = vraw + (long)b * HW;
    for (int j = threadIdx.x; j < TS * TS / 4; j += TPB) {
        const int r  = j / (TS / 4);
        const int c4 = j % (TS / 4);
        *(float4*)&vb[(ty0 + r) * WW + tx0 + c4 * 4] = tf4[j];
    }
    // flush far list to this block's private segment (no contention)
    const int n = min(lcnt, FCAP);
    int* fi = (int*)farbuf;
    if (threadIdx.x == 0) fi[blk] = n;
    for (int j = threadIdx.x; j < n; j += TPB) {
        fi[FIDX0 + blk * FCAP + j] = lidx[j];
        farbuf[FW0 + blk * FCAP + j] = lw[j];
    }
}

// Pass 1b: flush the (tiny) per-block far-vote segments with global atomics.
__global__ void far_scatter(const float* __restrict__ farbuf,
                            float* __restrict__ vraw) {
    const int s = blockIdx.x * blockDim.x + threadIdx.x;
    if (s >= NBLK * FCAP) return;
    const int blk = s / FCAP;
    const int j   = s % FCAP;
    const int* fi = (const int*)farbuf;
    if (j < min(fi[blk], FCAP))
        atomicAdd(&vraw[fi[FIDX0 + blk * FCAP + j]], farbuf[FW0 + blk * FCAP + j]);
}

// ---------------------------------------------------------------------------
// Pass 2: fused 15x15 box-sum, one 2D-tiled kernel. 64x64 output tile,
// halo-8 region (80x80) staged in LDS (zero-padded), row-sum (/DIVISOR,
// same summation pattern as the previously-passing two-pass version) into
// a second LDS buffer, then col-sum, write V. Intermediate never hits HBM.
// ---------------------------------------------------------------------------
__global__ __launch_bounds__(256)
void box2d(const float* __restrict__ in, float* __restrict__ out) {
    __shared__ float reg[BR * BR];  // 25.6 KB
    __shared__ float rs[BR * BT];   // 20 KB
    const int blk = blockIdx.x;     // 2048 = 8b * 256 tiles, XCD-affine
    const int b   = blk & 7;
    const int t   = blk >> 3;
    const int ty0 = (t >> 4) * BT;
    const int tx0 = (t & 15) * BT;
    const float* ib = in + (long)b * HW;

    // stage 80x80 region, zero outside image (f4 never straddles the edge)
    for (int o = threadIdx.x; o < BR * (BR / 4); o += 256) {
        const int r  = o / (BR / 4);
        const int c4 = o % (BR / 4);
        const int gy = ty0 - BH + r;
        const int gx = tx0 - BH + 4 * c4;
        float4 f = make_float4(0.f, 0.f, 0.f, 0.f);
        if (gy >= 0 && gy < HH && gx >= 0 && gx <= WW - 4)
            f = *(const float4*)&ib[(long)gy * WW + gx];
        *(float4*)&reg[r * BR + 4 * c4] = f;
    }
    __syncthreads();

    // phase A: rs[r][c] = (sum reg[r][c+1..c+15]) / D   (out col c <-> reg col c+8)
    for (int o = threadIdx.x; o < BR * (BT / 4); o += 256) {   // 1280 f4 tasks
        const int r = o >> 4;
        const int c = (o & 15) * 4;
        float v[20];
#pragma unroll
        for (int k = 0; k < 5; ++k) {
            float4 f = *(const float4*)&reg[r * BR + c + 4 * k];
            v[4 * k] = f.x; v[4 * k + 1] = f.y; v[4 * k + 2] = f.z; v[4 * k + 3] = f.w;
        }
        float s = 0.f;
#pragma unroll
        for (int k = 1; k <= 15; ++k) s += v[k];
        float4 q;
        q.x = s / DIVISOR;
        s += v[16] - v[1];  q.y = s / DIVISOR;
        s += v[17] - v[2];  q.z = s / DIVISOR;
        s += v[18] - v[3];  q.w = s / DIVISOR;
        *(float4*)&rs[r * BT + c] = q;
    }
    __syncthreads();

    // phase B: out[r][c] = sum rs[r+1..r+15][c]   (out row r <-> reg row r+8)
    float* ob = out + (long)b * HW;
    for (int o = threadIdx.x; o < BT * (BT / 4); o += 256) {   // 1024 f4 tasks
        const int r = o >> 4;
        const int c = (o & 15) * 4;
        float4 s = make_float4(0.f, 0.f, 0.f, 0.f);
#pragma unroll
        for (int k = 1; k <= 15; ++k) {
            float4 f = *(const float4*)&rs[(r + k) * BT + c];
            s.x += f.x; s.y += f.y; s.z += f.z; s.w += f.w;
        }
        *(float4*)&ob[(long)(ty0 + r) * WW + tx0 + c] = s;
    }
}

// ---------------------------------------------------------------------------
// Pass 3: fused 17x17 max-pool + peak decision. Same 2D tiling (-inf pad);
// the votes needed for isclose are the staged region's center -- no re-read.
// ---------------------------------------------------------------------------
__global__ __launch_bounds__(256)
void max2d_peaks(const float* __restrict__ votes, float* __restrict__ peaks) {
    __shared__ float reg[BR * BR];
    __shared__ float rm[BR * BT];
    const int blk = blockIdx.x;
    const int b   = blk & 7;
    const int t   = blk >> 3;
    const int ty0 = (t >> 4) * BT;
    const int tx0 = (t & 15) * BT;
    const float* ib = votes + (long)b * HW;

    for (int o = threadIdx.x; o < BR * (BR / 4); o += 256) {
        const int r  = o / (BR / 4);
        const int c4 = o % (BR / 4);
        const int gy = ty0 - BH + r;
        const int gx = tx0 - BH + 4 * c4;
        float4 f = make_float4(-INFINITY, -INFINITY, -INFINITY, -INFINITY);
        if (gy >= 0 && gy < HH && gx >= 0 && gx <= WW - 4)
            f = *(const float4*)&ib[(long)gy * WW + gx];
        *(float4*)&reg[r * BR + 4 * c4] = f;
    }
    __syncthreads();

    // phase A: rm[r][c] = max reg[r][c..c+16]
    for (int o = threadIdx.x; o < BR * (BT / 4); o += 256) {
        const int r = o >> 4;
        const int c = (o & 15) * 4;
        float v[20];
#pragma unroll
        for (int k = 0; k < 5; ++k) {
            float4 f = *(const float4*)&reg[r * BR + c + 4 * k];
            v[4 * k] = f.x; v[4 * k + 1] = f.y; v[4 * k + 2] = f.z; v[4 * k + 3] = f.w;
        }
        float m = v[3];
#pragma unroll
        for (int k = 4; k <= 16; ++k) m = fmaxf(m, v[k]);   // common cols c+3..c+16
        float4 q;
        q.x = fmaxf(fmaxf(m, v[0]),  fmaxf(v[1],  v[2]));
        q.y = fmaxf(fmaxf(m, v[1]),  fmaxf(v[2],  v[17]));
        q.z = fmaxf(fmaxf(m, v[2]),  fmaxf(v[17], v[18]));
        q.w = fmaxf(fmaxf(m, v[17]), fmaxf(v[18], v[19]));
        *(float4*)&rm[r * BT + c] = q;
    }
    __syncthreads();

    // phase B: dil = max rm[r..r+16][c]; compare vs staged votes center.
    float* pb = peaks + (long)b * HW;
    for (int o = threadIdx.x; o < BT * (BT / 4); o += 256) {
        const int r = o >> 4;
        const int c = (o & 15) * 4;
        float4 d = *(const float4*)&rm[r * BT + c];
#pragma unroll
        for (int k = 1; k <= 16; ++k) {
            float4 f = *(const float4*)&rm[(r + k) * BT + c];
            d.x = fmaxf(d.x, f.x); d.y = fmaxf(d.y, f.y);
            d.z = fmaxf(d.z, f.z); d.w = fmaxf(d.w, f.w);
        }
        const float4 vv = *(const float4*)&reg[(r + BH) * BR + c + BH];
        float4 q;
        // np.isclose(votes, dilated): |a-b| <= atol + rtol*|b|, b = dilated
        q.x = (fabsf(vv.x - d.x) <= (1e-8f + 1e-5f * fabsf(d.x)) && vv.x > THR_PEAKS) ? 1.f : 0.f;
        q.y = (fabsf(vv.y - d.y) <= (1e-8f + 1e-5f * fabsf(d.y)) && vv.y > THR_PEAKS) ? 1.f : 0.f;
        q.z = (fabsf(vv.z - d.z) <= (1e-8f + 1e-5f * fabsf(d.z)) && vv.z > THR_PEAKS) ? 1.f : 0.f;
        q.w = (fabsf(vv.w - d.w) <= (1e-8f + 1e-5f * fabsf(d.w)) && vv.w > THR_PEAKS) ? 1.f : 0.f;
        *(float4*)&pb[(long)(ty0 + r) * WW + tx0 + c] = q;
    }
}

extern "C" void kernel_launch(void* const* d_in, const int* in_sizes, int n_in,
                              void* d_out, int out_size, void* d_ws, size_t ws_size,
                              hipStream_t stream) {
    const float* kp  = (const float*)d_in[0];
    const float* off = (const float*)d_in[1];
    float* V = (float*)d_out;            // smoothed votes -> output 0
    float* P = (float*)d_out + TOTAL;    // peaks -> output 1 (far segments earlier)
    float* W = (float*)d_ws;             // 32 MB scratch: raw votes

    gather_votes<<<NBLK, TPB, 0, stream>>>(kp, off, W, P);      // W = raw votes
    far_scatter <<<NBLK * FCAP / 256, 256, 0, stream>>>(P, W);  // + far votes
    box2d       <<<NBLK, 256, 0, stream>>>(W, V);               // V = smoothed
    max2d_peaks <<<NBLK, 256, 0, stream>>>(V, P);               // P = peaks
}

// Round 11
// 215.502 us; speedup vs baseline: 1.8333x; 1.0309x over previous
//
#include <hip/hip_runtime.h>

constexpr int BB = 8;
constexpr int HH = 1024;
constexpr int WW = 1024;
constexpr int HW = HH * WW;
constexpr int TOTAL = BB * HW;

constexpr float RADIUS = 15.0f;
constexpr float THR_VOTES = 0.01f;
constexpr float THR_PEAKS = 0.2f;
// pi * 15^2 in double, rounded to f32 (matches jnp: votes / (np.pi*R*R))
constexpr float DIVISOR = 706.8583470577035f;

constexpr int TS = 64;          // gather output tile (16 KB LDS -> 8 blocks/CU)
constexpr int AP = 48;          // apron: votes with |delta|<=48 are "near"
constexpr int RG = TS + 2 * AP; // 160 input region per tile
constexpr int RGF = RG / 4;     // 40 float4 units per region row
constexpr int NF4 = RG * RGF;   // 6400 float4 units per region
constexpr int TPB = 256;
constexpr int NBLK = 2048;      // gather blocks
constexpr int FCAP = 128;       // far-vote capacity per block (expect ~11)

// far-list layout in the P region (ints): counts[NBLK], idx[NBLK*FCAP],
// then weights (floats) at FW0.
constexpr int FIDX0 = NBLK;
constexpr int FW0   = NBLK + NBLK * FCAP;

// 2D-fused smoothing/max tiles
constexpr int BT = 64;          // output tile
constexpr int BH = 8;           // halo (box needs 7, max needs 8; use 8)
constexpr int BR = BT + 2 * BH; // 80 staged region

// ---------------------------------------------------------------------------
// Pass 1: gather votes, float4-wide, XCD-affine (b = blk&7 -> XCD owns one
// batch image; tiles swept row-major keep apron re-reads in the XCD L2).
// Near votes (|delta|<=48) accumulate in the target tile's LDS. Far votes
// (~11 per block) stage in an LDS list counted by an LDS atomic -- NO global
// counter (round-7 lesson: ~20K wave-aggregated RMWs on ONE cache line
// serialize at its home L2 and pinned the kernel at ~237 us regardless of
// occupancy). Each block flushes its list to a private global segment.
// ---------------------------------------------------------------------------
__device__ __forceinline__ void process4(int px0, int py, float4 kw, float4 fox,
                                         float4 foy, int tx0, int ty0, int b,
                                         float* tile, int* lcnt,
                                         int* lidx, float* lw) {
    const float w[4]  = {kw.x, kw.y, kw.z, kw.w};
    const float ox[4] = {fox.x, fox.y, fox.z, fox.w};
    const float oy[4] = {foy.x, foy.y, foy.z, foy.w};
#pragma unroll
    for (int j = 0; j < 4; ++j) {
        const int px = px0 + j;
        // forbid FMA contraction: must match numpy's mul-then-add rounding,
        // else a .5-boundary vote lands in the adjacent cell.
        const float fx = __fadd_rn((float)px, __fmul_rn(RADIUS, ox[j]));
        const float fy = __fadd_rn((float)py, __fmul_rn(RADIUS, oy[j]));
        const int vx = (int)rintf(fx);   // round-half-even == np.round
        const int vy = (int)rintf(fy);
        if (vx < 0 || vx >= WW || vy < 0 || vy >= HH || w[j] < THR_VOTES) continue;
        const int dx = vx - px, dy = vy - py;
        if (dx >= -AP && dx <= AP && dy >= -AP && dy <= AP) {
            const int lx = vx - tx0, ly = vy - ty0;
            if (lx >= 0 && lx < TS && ly >= 0 && ly < TS)
                atomicAdd(&tile[ly * TS + lx], w[j]);
        } else if (px >= tx0 && px < tx0 + TS && py >= ty0 && py < ty0 + TS) {
            // far vote, owned by the SOURCE pixel's tile (exactly-once).
            const int slot = atomicAdd(lcnt, 1);   // LDS atomic: no global line
            if (slot < FCAP) {
                lidx[slot] = b * HW + vy * WW + vx;
                lw[slot]   = w[j];
            }
        }
    }
}

__global__ __launch_bounds__(TPB, 8)
void gather_votes(const float* __restrict__ kp, const float* __restrict__ off,
                  float* __restrict__ vraw, float* __restrict__ farbuf) {
    __shared__ float tile[TS * TS];   // 16 KB
    __shared__ int   lidx[FCAP];
    __shared__ float lw[FCAP];
    __shared__ int   lcnt;
    const int blk = blockIdx.x;       // 2048 blocks
    const int b   = blk & 7;          // batch == XCD (blk%8 round-robin)
    const int t   = blk >> 3;         // 256 tiles, row-major sweep per XCD
    const int ty0 = (t >> 4) * TS;
    const int tx0 = (t & 15) * TS;

    if (threadIdx.x == 0) lcnt = 0;
    float4* tf4 = (float4*)tile;
    for (int j = threadIdx.x; j < TS * TS / 4; j += TPB)
        tf4[j] = make_float4(0.f, 0.f, 0.f, 0.f);
    __syncthreads();

    const float* kpb  = kp  + (long)b * HW;
    const float* offx = off + (long)b * 2 * HW;
    const float* offy = offx + HW;

    for (int u = threadIdx.x; u < NF4; u += 2 * TPB) {
        const int uB = u + TPB;
        // decode unit A
        const int rA  = u / RGF;
        const int cA  = u - rA * RGF;
        const int pyA = ty0 - AP + rA;
        const int pxA = tx0 - AP + 4 * cA;   // multiple of 4: f4 never straddles edge
        const bool okA = (pyA >= 0 && pyA < HH && pxA >= 0 && pxA <= WW - 4);
        // decode unit B
        const int rB  = uB / RGF;
        const int cB  = uB - rB * RGF;
        const int pyB = ty0 - AP + rB;
        const int pxB = tx0 - AP + 4 * cB;
        const bool okB = (uB < NF4 && pyB >= 0 && pyB < HH && pxB >= 0 && pxB <= WW - 4);

        float4 kA, xA, yA, kB, xB, yB;
        if (okA) {
            const long p = (long)pyA * WW + pxA;
            kA = *(const float4*)(kpb + p);
            xA = *(const float4*)(offx + p);
            yA = *(const float4*)(offy + p);
        }
        if (okB) {
            const long p = (long)pyB * WW + pxB;
            kB = *(const float4*)(kpb + p);
            xB = *(const float4*)(offx + p);
            yB = *(const float4*)(offy + p);
        }
        if (okA) process4(pxA, pyA, kA, xA, yA, tx0, ty0, b, tile, &lcnt, lidx, lw);
        if (okB) process4(pxB, pyB, kB, xB, yB, tx0, ty0, b, tile, &lcnt, lidx, lw);
    }
    __syncthreads();

    // flush tile (plain coalesced stores; tiles partition the image)
    float* vb = vraw + (long)b * HW;
    for (int j = threadIdx.x; j < TS * TS / 4; j += TPB) {
        const int r  = j / (TS / 4);
        const int c4 = j % (TS / 4);
        *(float4*)&vb[(ty0 + r) * WW + tx0 + c4 * 4] = tf4[j];
    }
    // flush far list to this block's private segment (no contention)
    const int n = min(lcnt, FCAP);
    int* fi = (int*)farbuf;
    if (threadIdx.x == 0) fi[blk] = n;
    for (int j = threadIdx.x; j < n; j += TPB) {
        fi[FIDX0 + blk * FCAP + j] = lidx[j];
        farbuf[FW0 + blk * FCAP + j] = lw[j];
    }
}

// Pass 1b: flush the (tiny) per-block far-vote segments with global atomics.
__global__ void far_scatter(const float* __restrict__ farbuf,
                            float* __restrict__ vraw) {
    const int s = blockIdx.x * blockDim.x + threadIdx.x;
    if (s >= NBLK * FCAP) return;
    const int blk = s / FCAP;
    const int j   = s % FCAP;
    const int* fi = (const int*)farbuf;
    if (j < min(fi[blk], FCAP))
        atomicAdd(&vraw[fi[FIDX0 + blk * FCAP + j]], farbuf[FW0 + blk * FCAP + j]);
}

// ---------------------------------------------------------------------------
// Pass 2: fused 15x15 box-sum. 64x64 output tile + halo-8 region (80x80)
// staged in LDS. Phase A: row-sum (/DIVISOR) into rs. Phase B: SLIDING
// column sum, one (col, 16-row strip) per thread -- 30 batched scalar LDS
// reads + 2 ops/output (round-10 lesson: the naive 15-row re-read made
// phase B 8x more LDS traffic and 68 us; sliding restores the separable-
// pass efficiency inside the fusion).
// ---------------------------------------------------------------------------
__global__ __launch_bounds__(256)
void box2d(const float* __restrict__ in, float* __restrict__ out) {
    __shared__ float reg[BR * BR];  // 25.6 KB
    __shared__ float rs[BR * BT];   // 20 KB
    const int blk = blockIdx.x;     // 2048 = 8b * 256 tiles, XCD-affine
    const int b   = blk & 7;
    const int t   = blk >> 3;
    const int ty0 = (t >> 4) * BT;
    const int tx0 = (t & 15) * BT;
    const float* ib = in + (long)b * HW;

    // stage 80x80 region, zero outside image (f4 never straddles the edge)
    for (int o = threadIdx.x; o < BR * (BR / 4); o += 256) {
        const int r  = o / (BR / 4);
        const int c4 = o % (BR / 4);
        const int gy = ty0 - BH + r;
        const int gx = tx0 - BH + 4 * c4;
        float4 f = make_float4(0.f, 0.f, 0.f, 0.f);
        if (gy >= 0 && gy < HH && gx >= 0 && gx <= WW - 4)
            f = *(const float4*)&ib[(long)gy * WW + gx];
        *(float4*)&reg[r * BR + 4 * c4] = f;
    }
    __syncthreads();

    // phase A: rs[r][c] = (sum reg[r][c+1..c+15]) / D   (out col c <-> reg col c+8)
    for (int o = threadIdx.x; o < BR * (BT / 4); o += 256) {   // 1280 f4 tasks
        const int r = o >> 4;
        const int c = (o & 15) * 4;
        float v[20];
#pragma unroll
        for (int k = 0; k < 5; ++k) {
            float4 f = *(const float4*)&reg[r * BR + c + 4 * k];
            v[4 * k] = f.x; v[4 * k + 1] = f.y; v[4 * k + 2] = f.z; v[4 * k + 3] = f.w;
        }
        float s = 0.f;
#pragma unroll
        for (int k = 1; k <= 15; ++k) s += v[k];
        float4 q;
        q.x = s / DIVISOR;
        s += v[16] - v[1];  q.y = s / DIVISOR;
        s += v[17] - v[2];  q.z = s / DIVISOR;
        s += v[18] - v[3];  q.w = s / DIVISOR;
        *(float4*)&rs[r * BT + c] = q;
    }
    __syncthreads();

    // phase B: sliding col-sum. thread = (col, 16-row strip).
    // out row r needs rs rows r+1..r+15; strip r0 covers rows r0+1..r0+30.
    {
        const int col = threadIdx.x & 63;
        const int r0  = (threadIdx.x >> 6) * 16;
        float v[30];
#pragma unroll
        for (int k = 0; k < 30; ++k) v[k] = rs[(r0 + 1 + k) * BT + col];
        float s = 0.f;
#pragma unroll
        for (int k = 0; k < 15; ++k) s += v[k];
        float* ob = out + (long)b * HW + tx0 + col;
        ob[(long)(ty0 + r0) * WW] = s;
#pragma unroll
        for (int j = 1; j < 16; ++j) {
            s += v[14 + j] - v[j - 1];
            ob[(long)(ty0 + r0 + j) * WW] = s;
        }
    }
}

// ---------------------------------------------------------------------------
// Pass 3: fused 17x17 max-pool + peak decision. Phase B uses suffix/prefix
// max over a 32-row strip (46 fmax per 16 outputs); votes for isclose come
// from the staged region center -- no global re-read.
// ---------------------------------------------------------------------------
__global__ __launch_bounds__(256)
void max2d_peaks(const float* __restrict__ votes, float* __restrict__ peaks) {
    __shared__ float reg[BR * BR];
    __shared__ float rm[BR * BT];
    const int blk = blockIdx.x;
    const int b   = blk & 7;
    const int t   = blk >> 3;
    const int ty0 = (t >> 4) * BT;
    const int tx0 = (t & 15) * BT;
    const float* ib = votes + (long)b * HW;

    for (int o = threadIdx.x; o < BR * (BR / 4); o += 256) {
        const int r  = o / (BR / 4);
        const int c4 = o % (BR / 4);
        const int gy = ty0 - BH + r;
        const int gx = tx0 - BH + 4 * c4;
        float4 f = make_float4(-INFINITY, -INFINITY, -INFINITY, -INFINITY);
        if (gy >= 0 && gy < HH && gx >= 0 && gx <= WW - 4)
            f = *(const float4*)&ib[(long)gy * WW + gx];
        *(float4*)&reg[r * BR + 4 * c4] = f;
    }
    __syncthreads();

    // phase A: rm[r][c] = max reg[r][c..c+16]
    for (int o = threadIdx.x; o < BR * (BT / 4); o += 256) {
        const int r = o >> 4;
        const int c = (o & 15) * 4;
        float v[20];
#pragma unroll
        for (int k = 0; k < 5; ++k) {
            float4 f = *(const float4*)&reg[r * BR + c + 4 * k];
            v[4 * k] = f.x; v[4 * k + 1] = f.y; v[4 * k + 2] = f.z; v[4 * k + 3] = f.w;
        }
        float m = v[3];
#pragma unroll
        for (int k = 4; k <= 16; ++k) m = fmaxf(m, v[k]);   // common cols c+3..c+16
        float4 q;
        q.x = fmaxf(fmaxf(m, v[0]),  fmaxf(v[1],  v[2]));
        q.y = fmaxf(fmaxf(m, v[1]),  fmaxf(v[2],  v[17]));
        q.z = fmaxf(fmaxf(m, v[2]),  fmaxf(v[17], v[18]));
        q.w = fmaxf(fmaxf(m, v[17]), fmaxf(v[18], v[19]));
        *(float4*)&rm[r * BT + c] = q;
    }
    __syncthreads();

    // phase B: thread = (col, 16-row strip). out row r needs rm rows r..r+16;
    // strip covers rm rows r0..r0+31. Every window j (0..15) = v[j..j+16]
    // contains v[16]: suffix suf[j]=max(v[j..16]), prefix pre=max(v[17..16+j]).
    {
        const int col = threadIdx.x & 63;
        const int r0  = (threadIdx.x >> 6) * 16;
        float v[32];
#pragma unroll
        for (int k = 0; k < 32; ++k) v[k] = rm[(r0 + k) * BT + col];
        float suf[17];
        suf[16] = v[16];
#pragma unroll
        for (int k = 15; k >= 0; --k) suf[k] = fmaxf(v[k], suf[k + 1]);

        float* pb = peaks + (long)b * HW + tx0 + col;
        float pre = -INFINITY;
#pragma unroll
        for (int j = 0; j < 16; ++j) {
            if (j > 0) pre = fmaxf(pre, v[16 + j]);
            const float d = (j > 0) ? fmaxf(suf[j], pre) : suf[0];
            const float vv = reg[(r0 + j + BH) * BR + col + BH];
            // np.isclose(votes, dilated): |a-b| <= atol + rtol*|b|, b = dilated
            const bool close = fabsf(vv - d) <= (1e-8f + 1e-5f * fabsf(d));
            pb[(long)(ty0 + r0 + j) * WW] = (close && vv > THR_PEAKS) ? 1.0f : 0.0f;
        }
    }
}

extern "C" void kernel_launch(void* const* d_in, const int* in_sizes, int n_in,
                              void* d_out, int out_size, void* d_ws, size_t ws_size,
                              hipStream_t stream) {
    const float* kp  = (const float*)d_in[0];
    const float* off = (const float*)d_in[1];
    float* V = (float*)d_out;            // smoothed votes -> output 0
    float* P = (float*)d_out + TOTAL;    // peaks -> output 1 (far segments earlier)
    float* W = (float*)d_ws;             // 32 MB scratch: raw votes

    gather_votes<<<NBLK, TPB, 0, stream>>>(kp, off, W, P);      // W = raw votes
    far_scatter <<<NBLK * FCAP / 256, 256, 0, stream>>>(P, W);  // + far votes
    box2d       <<<NBLK, 256, 0, stream>>>(W, V);               // V = smoothed
    max2d_peaks <<<NBLK, 256, 0, stream>>>(V, P);               // P = peaks
}